// Round 5
// baseline (470.933 us; speedup 1.0000x reference)
//
#include <hip/hip_runtime.h>
#include <math.h>

// RWKV WKV forward — chunked scan, register ping-pong prefetch pinned with
// sched_barrier(0).
//
// R3: compiler SANK the register prefetch (VGPR=32) -> latency-bound.
// R4: LDS-DMA + barriers + mid-loop vmcnt drains -> same 110 us; pass3's
//     vmcnt count included output stores -> waited on store retirement.
// R5: no LDS, no barriers, no explicit waitcnt. Loads pinned at issue site
//     by __builtin_amdgcn_sched_barrier(0) after each load group; the
//     waitcnt for a buffer is auto-inserted before its first use (one
//     compute-group of lead time). TLP does the rest: NC=32 chunks ->
//     8192 waves = 8/SIMD; __launch_bounds__(256,8) keeps VGPR <= 64.

#define WKV_Tc 2048
#define WKV_Hc 2048
#define WKV_BHc 16384
#define WKV_Un 8   // timesteps per prefetch group

__device__ __forceinline__ void wkv_update(float& a, float& bs, float& e,
                                           float w, float kt, float vt) {
    float ew = e + w;
    float m2 = fmaxf(ew, kt);
    float s1 = __expf(ew - m2);
    float s2 = __expf(kt - m2);
    a  = fmaf(s1, a, s2 * vt);
    bs = fmaf(s1, bs, s2);
    e  = m2;
}

// ---- K1: chunk-local state from identity ----
template<int L>
__global__ __launch_bounds__(256, 8)
void wkv_pass1(const float* __restrict__ k_, const float* __restrict__ v_,
               const float* __restrict__ td,
               float* __restrict__ pa, float* __restrict__ pb,
               float* __restrict__ pe)
{
    const uint32_t ch = blockIdx.x * 256u + threadIdx.x;   // 0..BH-1
    const uint32_t c  = blockIdx.y;
    const uint32_t h  = ch & (WKV_Hc - 1);
    const uint32_t b  = ch >> 11;
    const float w = -__expf(td[h]);

    // 32-bit element offset (max 33.5M < 2^32): lets hipcc use saddr+voffset.
    const uint32_t off = b * (uint32_t)(WKV_Tc * WKV_Hc)
                       + c * (uint32_t)(L * WKV_Hc) + h;

    float a = 0.f, bs = 0.f, e = -INFINITY;
    float kA[WKV_Un], vA[WKV_Un], kB[WKV_Un], vB[WKV_Un];

    #pragma unroll
    for (int i = 0; i < WKV_Un; ++i) {
        kA[i] = k_[off + (uint32_t)i * WKV_Hc];
        vA[i] = v_[off + (uint32_t)i * WKV_Hc];
    }
    __builtin_amdgcn_sched_barrier(0);   // pin issue of group 0

    #pragma unroll
    for (int t0 = 0; t0 < L; t0 += 2 * WKV_Un) {
        #pragma unroll
        for (int i = 0; i < WKV_Un; ++i) {
            const uint32_t o = off + (uint32_t)(t0 + WKV_Un + i) * WKV_Hc;
            kB[i] = k_[o]; vB[i] = v_[o];
        }
        __builtin_amdgcn_sched_barrier(0);   // B issued before A-compute
        #pragma unroll
        for (int i = 0; i < WKV_Un; ++i) wkv_update(a, bs, e, w, kA[i], vA[i]);
        if (t0 + 2 * WKV_Un < L) {
            #pragma unroll
            for (int i = 0; i < WKV_Un; ++i) {
                const uint32_t o = off + (uint32_t)(t0 + 2 * WKV_Un + i) * WKV_Hc;
                kA[i] = k_[o]; vA[i] = v_[o];
            }
            __builtin_amdgcn_sched_barrier(0);  // A' issued before B-compute
        }
        #pragma unroll
        for (int i = 0; i < WKV_Un; ++i) wkv_update(a, bs, e, w, kB[i], vB[i]);
    }

    const uint32_t idx = c * (uint32_t)WKV_BHc + ch;
    pa[idx] = a; pb[idx] = bs; pe[idx] = e;
}

// ---- K2: serial combine; P[c] <- incoming state S_c ----
__global__ __launch_bounds__(256)
void wkv_combine(float* __restrict__ pa, float* __restrict__ pb,
                 float* __restrict__ pe, const float* __restrict__ td,
                 int NC, int L)
{
    const uint32_t ch = blockIdx.x * 256u + threadIdx.x;
    const float w  = -__expf(td[ch & (WKV_Hc - 1)]);
    const float Lw = w * (float)L;

    float a = 0.f, bs = 0.f, e = -INFINITY;
    for (int c = 0; c < NC; ++c) {
        const uint32_t idx = (uint32_t)c * WKV_BHc + ch;
        float qa = pa[idx], qb = pb[idx], qe = pe[idx];
        pa[idx] = a; pb[idx] = bs; pe[idx] = e;
        float ed = e + Lw;
        float m  = fmaxf(ed, qe);
        float s1 = __expf(ed - m);
        float s2 = __expf(qe - m);
        a  = fmaf(s1, a, s2 * qa);
        bs = fmaf(s1, bs, s2 * qb);
        e  = m;
    }
}

// ---- K3: outputs from incoming state ----
template<int L>
__global__ __launch_bounds__(256, 8)
void wkv_pass3(const float* __restrict__ k_, const float* __restrict__ v_,
               const float* __restrict__ td, const float* __restrict__ tf,
               const float* __restrict__ pa, const float* __restrict__ pb,
               const float* __restrict__ pe,
               float* __restrict__ out)
{
    const uint32_t ch = blockIdx.x * 256u + threadIdx.x;
    const uint32_t c  = blockIdx.y;
    const uint32_t h  = ch & (WKV_Hc - 1);
    const uint32_t b  = ch >> 11;
    const float u = tf[h];
    const float w = -__expf(td[h]);

    const uint32_t idx = c * (uint32_t)WKV_BHc + ch;
    float a = pa[idx], bs = pb[idx], e = pe[idx];

    const uint32_t off = b * (uint32_t)(WKV_Tc * WKV_Hc)
                       + c * (uint32_t)(L * WKV_Hc) + h;

    auto step = [&](float kt, float vt, uint32_t o) {
        float uk  = u + kt;
        float m   = fmaxf(e, uk);
        float wt  = __expf(uk - m);
        float sc  = __expf(e - m);
        float num = fmaf(wt, vt, a * sc);
        float den = fmaf(bs, sc, wt);
        out[o] = num * __builtin_amdgcn_rcpf(den);   // fire-and-forget
        wkv_update(a, bs, e, w, kt, vt);
    };

    float kA[WKV_Un], vA[WKV_Un], kB[WKV_Un], vB[WKV_Un];
    #pragma unroll
    for (int i = 0; i < WKV_Un; ++i) {
        kA[i] = k_[off + (uint32_t)i * WKV_Hc];
        vA[i] = v_[off + (uint32_t)i * WKV_Hc];
    }
    __builtin_amdgcn_sched_barrier(0);

    #pragma unroll
    for (int t0 = 0; t0 < L; t0 += 2 * WKV_Un) {
        #pragma unroll
        for (int i = 0; i < WKV_Un; ++i) {
            const uint32_t o = off + (uint32_t)(t0 + WKV_Un + i) * WKV_Hc;
            kB[i] = k_[o]; vB[i] = v_[o];
        }
        __builtin_amdgcn_sched_barrier(0);
        #pragma unroll
        for (int i = 0; i < WKV_Un; ++i)
            step(kA[i], vA[i], off + (uint32_t)(t0 + i) * WKV_Hc);
        if (t0 + 2 * WKV_Un < L) {
            #pragma unroll
            for (int i = 0; i < WKV_Un; ++i) {
                const uint32_t o = off + (uint32_t)(t0 + 2 * WKV_Un + i) * WKV_Hc;
                kA[i] = k_[o]; vA[i] = v_[o];
            }
            __builtin_amdgcn_sched_barrier(0);
        }
        #pragma unroll
        for (int i = 0; i < WKV_Un; ++i)
            step(kB[i], vB[i], off + (uint32_t)(t0 + WKV_Un + i) * WKV_Hc);
    }
}

extern "C" void kernel_launch(void* const* d_in, const int* in_sizes, int n_in,
                              void* d_out, int out_size, void* d_ws, size_t ws_size,
                              hipStream_t stream) {
    const float* key   = (const float*)d_in[0];
    const float* value = (const float*)d_in[1];
    const float* td    = (const float*)d_in[2];
    const float* tf    = (const float*)d_in[3];
    float* out = (float*)d_out;

    const bool big = (size_t)3 * sizeof(float) * WKV_BHc * 32 <= ws_size;
    const int NC = big ? 32 : 16;
    const int L  = WKV_Tc / NC;

    float* pa = (float*)d_ws;
    float* pb = pa + (size_t)WKV_BHc * NC;
    float* pe = pb + (size_t)WKV_BHc * NC;

    dim3 grid(WKV_BHc / 256, NC);
    if (big) {
        wkv_pass1<64><<<grid, 256, 0, stream>>>(key, value, td, pa, pb, pe);
        wkv_combine<<<WKV_BHc / 256, 256, 0, stream>>>(pa, pb, pe, td, NC, L);
        wkv_pass3<64><<<grid, 256, 0, stream>>>(key, value, td, tf, pa, pb, pe, out);
    } else {
        wkv_pass1<128><<<grid, 256, 0, stream>>>(key, value, td, pa, pb, pe);
        wkv_combine<<<WKV_BHc / 256, 256, 0, stream>>>(pa, pb, pe, td, NC, L);
        wkv_pass3<128><<<grid, 256, 0, stream>>>(key, value, td, tf, pa, pb, pe, out);
    }
}

// Round 8
// 414.115 us; speedup vs baseline: 1.1372x; 1.1372x over previous
//
#include <hip/hip_runtime.h>
#include <math.h>

// RWKV WKV forward — chunked scan, float4-across-channels.
//
// History: R3 (scalar reg prefetch, sunk, VGPR=32) / R4 (LDS-DMA) / R5
// (pinned prefetch, spilled under 64-VGPR cap) all bottomed at ~1.3-2.2 TB/s:
// 256 B/wave scalar requests starve MLP. Fix: thread owns 4 consecutive
// channels -> k/v are dwordx4 (1 KB/wave/request), 1-step-ahead prefetch
// pinned by sched_barrier(0), cap 128 VGPR (no spill).
//
//   pass1: per (4-ch group, chunk c) chunk-local state (a,b,e) from identity.
//   k2a:   per (ch, group g): aggregate A_g of the group's CPG chunks.
//   k2b:   per ch: serial scan over 8 groups; A_g <- incoming state GI_g.
//   k2c:   per (ch, g): from GI_g, rewrite P[c] <- incoming state of chunk c.
//   pass3: per (4-ch group, chunk c): start from P[c], emit outputs.

#define TT 2048
#define HH 2048
#define BHc 16384
#define H4 512          // HH/4
#define NGRP 8

struct __align__(16) f4 { float v[4]; };

__device__ __forceinline__ void upd1(float& a, float& b, float& e,
                                     float w, float k, float vv) {
    float ew = e + w;
    float m  = fmaxf(ew, k);
    float s1 = __expf(ew - m);
    float s2 = __expf(k - m);
    a = fmaf(s1, a, s2 * vv);
    b = fmaf(s1, b, s2);
    e = m;
}

// state <- compose(state decayed by dLw, Q)   [Q must be finite]
__device__ __forceinline__ void compose(float& a, float& b, float& e,
                                        float qa, float qb, float qe, float dLw) {
    float ed = e + dLw;
    float m  = fmaxf(ed, qe);
    float s1 = __expf(ed - m);     // 0 when e = -inf
    float s2 = __expf(qe - m);
    a = fmaf(s1, a, s2 * qa);
    b = fmaf(s1, b, s2 * qb);
    e = m;
}

// ---- pass1: chunk-local state from identity ----
template<int L>
__global__ __launch_bounds__(256, 4)
void wkv_pass1(const float* __restrict__ k_, const float* __restrict__ v_,
               const float* __restrict__ td,
               float* __restrict__ pa, float* __restrict__ pb,
               float* __restrict__ pe)
{
    const uint32_t t4  = blockIdx.x * 256u + threadIdx.x;  // channel-group id
    const uint32_t c   = blockIdx.y;
    const uint32_t ch0 = t4 * 4u;
    const uint32_t h0  = ch0 & (HH - 1);
    const uint32_t b   = ch0 >> 11;

    const f4 wr = *(const f4*)(td + h0);
    float w[4], a[4], bs[4], e[4];
    #pragma unroll
    for (int j = 0; j < 4; ++j) {
        w[j] = -__expf(wr.v[j]); a[j] = 0.f; bs[j] = 0.f; e[j] = -INFINITY;
    }

    const uint32_t off4 = (b * (uint32_t)(TT * HH) + c * (uint32_t)(L * HH) + h0) >> 2;
    const f4* K4 = (const f4*)k_;
    const f4* V4 = (const f4*)v_;

    f4 kc = K4[off4], vc = V4[off4];
    #pragma unroll
    for (int t = 0; t < L; ++t) {
        f4 kn, vn;
        if (t + 1 < L) {
            kn = K4[off4 + (uint32_t)(t + 1) * H4];
            vn = V4[off4 + (uint32_t)(t + 1) * H4];
        }
        __builtin_amdgcn_sched_barrier(0);   // pin prefetch before compute
        #pragma unroll
        for (int j = 0; j < 4; ++j) upd1(a[j], bs[j], e[j], w[j], kc.v[j], vc.v[j]);
        if (t + 1 < L) { kc = kn; vc = vn; }
    }

    const uint32_t pi4 = (c * (uint32_t)BHc + ch0) >> 2;
    f4 oa, ob, oe;
    #pragma unroll
    for (int j = 0; j < 4; ++j) { oa.v[j] = a[j]; ob.v[j] = bs[j]; oe.v[j] = e[j]; }
    ((f4*)pa)[pi4] = oa; ((f4*)pb)[pi4] = ob; ((f4*)pe)[pi4] = oe;
}

// ---- k2a: group aggregates A_g (from identity) ----
__global__ __launch_bounds__(256, 2)
void wkv_k2a(const float* __restrict__ pa, const float* __restrict__ pb,
             const float* __restrict__ pe,
             float* __restrict__ aa, float* __restrict__ ab,
             float* __restrict__ ae,
             const float* __restrict__ td, int CPG, int L)
{
    const uint32_t id = blockIdx.x * 256u + threadIdx.x;   // BHc * NGRP threads
    const uint32_t ch = id & (BHc - 1);
    const uint32_t g  = id >> 14;
    const float w  = -__expf(td[ch & (HH - 1)]);
    const float Lw = w * (float)L;

    float a = 0.f, b = 0.f, e = -INFINITY;
    for (int c = (int)g * CPG; c < (int)(g + 1) * CPG; ++c) {
        const uint32_t idx = (uint32_t)c * BHc + ch;
        compose(a, b, e, pa[idx], pb[idx], pe[idx], Lw);
    }
    const uint32_t gi = g * BHc + ch;
    aa[gi] = a; ab[gi] = b; ae[gi] = e;
}

// ---- k2b: scan groups; A_g <- incoming state GI_g ----
__global__ __launch_bounds__(256, 2)
void wkv_k2b(float* __restrict__ aa, float* __restrict__ ab,
             float* __restrict__ ae, const float* __restrict__ td, int LC)
{
    const uint32_t ch = blockIdx.x * 256u + threadIdx.x;
    const float w   = -__expf(td[ch & (HH - 1)]);
    const float GLw = w * (float)LC;                      // LC = L * CPG

    float a = 0.f, b = 0.f, e = -INFINITY;
    for (int g = 0; g < NGRP; ++g) {
        const uint32_t gi = (uint32_t)g * BHc + ch;
        float qa = aa[gi], qb = ab[gi], qe = ae[gi];
        aa[gi] = a; ab[gi] = b; ae[gi] = e;
        compose(a, b, e, qa, qb, qe, GLw);
    }
}

// ---- k2c: from GI_g, rewrite P[c] <- incoming state of chunk c ----
__global__ __launch_bounds__(256, 2)
void wkv_k2c(float* __restrict__ pa, float* __restrict__ pb,
             float* __restrict__ pe,
             const float* __restrict__ aa, const float* __restrict__ ab,
             const float* __restrict__ ae,
             const float* __restrict__ td, int CPG, int L)
{
    const uint32_t id = blockIdx.x * 256u + threadIdx.x;
    const uint32_t ch = id & (BHc - 1);
    const uint32_t g  = id >> 14;
    const float w  = -__expf(td[ch & (HH - 1)]);
    const float Lw = w * (float)L;

    const uint32_t gi = g * BHc + ch;
    float a = aa[gi], b = ab[gi], e = ae[gi];
    for (int c = (int)g * CPG; c < (int)(g + 1) * CPG; ++c) {
        const uint32_t idx = (uint32_t)c * BHc + ch;
        float qa = pa[idx], qb = pb[idx], qe = pe[idx];
        pa[idx] = a; pb[idx] = b; pe[idx] = e;
        compose(a, b, e, qa, qb, qe, Lw);
    }
}

// ---- pass3: outputs from incoming state ----
template<int L>
__global__ __launch_bounds__(256, 4)
void wkv_pass3(const float* __restrict__ k_, const float* __restrict__ v_,
               const float* __restrict__ td, const float* __restrict__ tf,
               const float* __restrict__ pa, const float* __restrict__ pb,
               const float* __restrict__ pe,
               float* __restrict__ out)
{
    const uint32_t t4  = blockIdx.x * 256u + threadIdx.x;
    const uint32_t c   = blockIdx.y;
    const uint32_t ch0 = t4 * 4u;
    const uint32_t h0  = ch0 & (HH - 1);
    const uint32_t b   = ch0 >> 11;

    const f4 wr = *(const f4*)(td + h0);
    const f4 ur = *(const f4*)(tf + h0);
    const uint32_t pi4 = (c * (uint32_t)BHc + ch0) >> 2;
    const f4 ra = ((const f4*)pa)[pi4];
    const f4 rb = ((const f4*)pb)[pi4];
    const f4 re = ((const f4*)pe)[pi4];

    float w[4], u[4], a[4], bs[4], e[4];
    #pragma unroll
    for (int j = 0; j < 4; ++j) {
        w[j] = -__expf(wr.v[j]); u[j] = ur.v[j];
        a[j] = ra.v[j]; bs[j] = rb.v[j]; e[j] = re.v[j];
    }

    const uint32_t off4 = (b * (uint32_t)(TT * HH) + c * (uint32_t)(L * HH) + h0) >> 2;
    const f4* K4 = (const f4*)k_;
    const f4* V4 = (const f4*)v_;
    f4*       O4 = (f4*)out;

    f4 kc = K4[off4], vc = V4[off4];
    #pragma unroll
    for (int t = 0; t < L; ++t) {
        f4 kn, vn;
        if (t + 1 < L) {
            kn = K4[off4 + (uint32_t)(t + 1) * H4];
            vn = V4[off4 + (uint32_t)(t + 1) * H4];
        }
        __builtin_amdgcn_sched_barrier(0);
        f4 o;
        #pragma unroll
        for (int j = 0; j < 4; ++j) {
            float kt = kc.v[j], vt = vc.v[j];
            float uk  = u[j] + kt;
            float m   = fmaxf(e[j], uk);
            float wt  = __expf(uk - m);
            float sc  = __expf(e[j] - m);
            float num = fmaf(wt, vt, a[j] * sc);
            float den = fmaf(bs[j], sc, wt);
            o.v[j] = num * __builtin_amdgcn_rcpf(den);
            upd1(a[j], bs[j], e[j], w[j], kt, vt);
        }
        O4[off4 + (uint32_t)t * H4] = o;     // fire-and-forget
        if (t + 1 < L) { kc = kn; vc = vn; }
    }
}

extern "C" void kernel_launch(void* const* d_in, const int* in_sizes, int n_in,
                              void* d_out, int out_size, void* d_ws, size_t ws_size,
                              hipStream_t stream) {
    const float* key   = (const float*)d_in[0];
    const float* value = (const float*)d_in[1];
    const float* td    = (const float*)d_in[2];
    const float* tf    = (const float*)d_in[3];
    float* out = (float*)d_out;

    // workspace: P (3 * BH * NC) + A (3 * BH * 8) floats
    int NC = 64;
    while (NC > 8 &&
           (size_t)3 * sizeof(float) * BHc * (NC + NGRP) > ws_size) NC >>= 1;
    const int L   = TT / NC;
    const int CPG = NC / NGRP;

    float* pa = (float*)d_ws;
    float* pb = pa + (size_t)BHc * NC;
    float* pe = pb + (size_t)BHc * NC;
    float* aa = pe + (size_t)BHc * NC;
    float* ab = aa + (size_t)BHc * NGRP;
    float* ae = ab + (size_t)BHc * NGRP;

    dim3 grid1(BHc / 4 / 256, NC);         // (16, NC)
    const int gk2 = BHc * NGRP / 256;      // 512 blocks
    const int gkb = BHc / 256;             // 64 blocks

    switch (L) {
    case 32:
        wkv_pass1<32><<<grid1, 256, 0, stream>>>(key, value, td, pa, pb, pe);
        break;
    case 64:
        wkv_pass1<64><<<grid1, 256, 0, stream>>>(key, value, td, pa, pb, pe);
        break;
    default:
        wkv_pass1<128><<<grid1, 256, 0, stream>>>(key, value, td, pa, pb, pe);
        break;
    }
    wkv_k2a<<<gk2, 256, 0, stream>>>(pa, pb, pe, aa, ab, ae, td, CPG, L);
    wkv_k2b<<<gkb, 256, 0, stream>>>(aa, ab, ae, td, L * CPG);
    wkv_k2c<<<gk2, 256, 0, stream>>>(pa, pb, pe, aa, ab, ae, td, CPG, L);
    switch (L) {
    case 32:
        wkv_pass3<32><<<grid1, 256, 0, stream>>>(key, value, td, tf, pa, pb, pe, out);
        break;
    case 64:
        wkv_pass3<64><<<grid1, 256, 0, stream>>>(key, value, td, tf, pa, pb, pe, out);
        break;
    default:
        wkv_pass3<128><<<grid1, 256, 0, stream>>>(key, value, td, tf, pa, pb, pe, out);
        break;
    }
}

// Round 9
// 398.967 us; speedup vs baseline: 1.1804x; 1.0380x over previous
//
#include <hip/hip_runtime.h>
#include <math.h>

// RWKV WKV forward — chunked scan, block-contiguous row streaming.
//
// R8 evidence: BW cap ~2.3 TB/s when a block consumes an interleaved
// fraction of each 8KB row (1KB frac -> 1.25 TB/s, 4KB -> 2.2 TB/s).
// Fix: 512-thread blocks, thread owns 4 channels -> block covers the FULL
// 2048-channel row; the t-walk streams the chunk's [L x 8KB] region
// contiguously (m13-style). Depth-2 pinned prefetch, no spill.
//
//   pass1: per (b,c) block: chunk-local state from identity.      (L steps)
//   k2a/k2b/k2c: hierarchical combine -> P[c] = incoming state.
//   pass3: per (b,c) block: outputs from incoming state.

#define TT 2048
#define HH 2048
#define BHc 16384
#define H4 512           // HH/4 (f4 per row)
#define CH4 4096         // BHc/4
#define CPG 8

struct __align__(16) f4 { float v[4]; };

__device__ __forceinline__ void upd1(float& a, float& b, float& e,
                                     float w, float k, float vv) {
    float ew = e + w;
    float m  = fmaxf(ew, k);
    float s1 = __expf(ew - m);
    float s2 = __expf(k - m);
    a = fmaf(s1, a, s2 * vv);
    b = fmaf(s1, b, s2);
    e = m;
}

__device__ __forceinline__ void compose(float& a, float& b, float& e,
                                        float qa, float qb, float qe, float dLw) {
    float ed = e + dLw;
    float m  = fmaxf(ed, qe);
    float s1 = __expf(ed - m);     // 0 when e = -inf
    float s2 = __expf(qe - m);
    a = fmaf(s1, a, s2 * qa);
    b = fmaf(s1, b, s2 * qb);
    e = m;
}

// ---- pass1: chunk-local state from identity ----
template<int L>
__global__ __launch_bounds__(512, 4)
void wkv_pass1(const float* __restrict__ k_, const float* __restrict__ v_,
               const float* __restrict__ td,
               float* __restrict__ pa, float* __restrict__ pb,
               float* __restrict__ pe)
{
    constexpr uint32_t NCk = TT / L;
    const uint32_t tid = threadIdx.x;           // 0..511
    const uint32_t b   = blockIdx.x / NCk;
    const uint32_t c   = blockIdx.x % NCk;      // NCk pow2 -> shift/mask
    const uint32_t h0  = tid * 4u;

    const f4 wr = *(const f4*)(td + h0);
    float w[4], a[4], bs[4], e[4];
    #pragma unroll
    for (int j = 0; j < 4; ++j) {
        w[j] = -__expf(wr.v[j]); a[j] = 0.f; bs[j] = 0.f; e[j] = -INFINITY;
    }

    const uint32_t off4 = (b * (uint32_t)(TT * HH) + c * (uint32_t)(L * HH)) / 4u + tid;
    const f4* K4 = (const f4*)k_;
    const f4* V4 = (const f4*)v_;

    // depth-2 pinned prefetch (static rotation via full unroll)
    f4 k0 = K4[off4],           v0 = V4[off4];
    f4 k1 = K4[off4 + H4],      v1 = V4[off4 + H4];
    #pragma unroll
    for (int t = 0; t < L; ++t) {
        f4 k2, v2;
        if (t + 2 < L) {
            k2 = K4[off4 + (uint32_t)(t + 2) * H4];
            v2 = V4[off4 + (uint32_t)(t + 2) * H4];
        }
        __builtin_amdgcn_sched_barrier(0);      // pin prefetch issue
        #pragma unroll
        for (int j = 0; j < 4; ++j) upd1(a[j], bs[j], e[j], w[j], k0.v[j], v0.v[j]);
        k0 = k1; v0 = v1;
        if (t + 2 < L) { k1 = k2; v1 = v2; }
    }

    const uint32_t p4 = (c * (uint32_t)BHc + b * (uint32_t)HH) / 4u + tid;
    f4 oa, ob, oe;
    #pragma unroll
    for (int j = 0; j < 4; ++j) { oa.v[j] = a[j]; ob.v[j] = bs[j]; oe.v[j] = e[j]; }
    ((f4*)pa)[p4] = oa; ((f4*)pb)[p4] = ob; ((f4*)pe)[p4] = oe;
}

// ---- k2a: per (ch4, group) aggregate of CPG chunks (identity start) ----
__global__ __launch_bounds__(256, 2)
void wkv_k2a(const float* __restrict__ pa, const float* __restrict__ pb,
             const float* __restrict__ pe,
             float* __restrict__ aa, float* __restrict__ ab,
             float* __restrict__ ae,
             const float* __restrict__ td, int L)
{
    const uint32_t id  = blockIdx.x * 256u + threadIdx.x;  // CH4 * NGRP
    const uint32_t ch4 = id & (CH4 - 1);
    const uint32_t g   = id >> 12;
    const uint32_t h0  = (ch4 * 4u) & (HH - 1);

    const f4 wr = *(const f4*)(td + h0);
    float Lw[4], a[4], b[4], e[4];
    #pragma unroll
    for (int j = 0; j < 4; ++j) {
        Lw[j] = -__expf(wr.v[j]) * (float)L;
        a[j] = 0.f; b[j] = 0.f; e[j] = -INFINITY;
    }

    for (int c = (int)g * CPG; c < (int)(g + 1) * CPG; ++c) {
        const uint32_t i4 = (uint32_t)c * CH4 + ch4;
        const f4 qa = ((const f4*)pa)[i4];
        const f4 qb = ((const f4*)pb)[i4];
        const f4 qe = ((const f4*)pe)[i4];
        #pragma unroll
        for (int j = 0; j < 4; ++j)
            compose(a[j], b[j], e[j], qa.v[j], qb.v[j], qe.v[j], Lw[j]);
    }
    const uint32_t gi = g * CH4 + ch4;
    f4 oa, ob, oe;
    #pragma unroll
    for (int j = 0; j < 4; ++j) { oa.v[j] = a[j]; ob.v[j] = b[j]; oe.v[j] = e[j]; }
    ((f4*)aa)[gi] = oa; ((f4*)ab)[gi] = ob; ((f4*)ae)[gi] = oe;
}

// ---- k2b: scan groups; A_g <- incoming group state ----
__global__ __launch_bounds__(256, 2)
void wkv_k2b(float* __restrict__ aa, float* __restrict__ ab,
             float* __restrict__ ae, const float* __restrict__ td,
             int NGRP, int LC)
{
    const uint32_t ch4 = blockIdx.x * 256u + threadIdx.x;  // 0..CH4-1
    const uint32_t h0  = (ch4 * 4u) & (HH - 1);
    const f4 wr = *(const f4*)(td + h0);
    float GLw[4], a[4], b[4], e[4];
    #pragma unroll
    for (int j = 0; j < 4; ++j) {
        GLw[j] = -__expf(wr.v[j]) * (float)LC;
        a[j] = 0.f; b[j] = 0.f; e[j] = -INFINITY;
    }

    for (int g = 0; g < NGRP; ++g) {
        const uint32_t gi = (uint32_t)g * CH4 + ch4;
        const f4 qa = ((const f4*)aa)[gi];
        const f4 qb = ((const f4*)ab)[gi];
        const f4 qe = ((const f4*)ae)[gi];
        f4 oa, ob, oe;
        #pragma unroll
        for (int j = 0; j < 4; ++j) { oa.v[j] = a[j]; ob.v[j] = b[j]; oe.v[j] = e[j]; }
        ((f4*)aa)[gi] = oa; ((f4*)ab)[gi] = ob; ((f4*)ae)[gi] = oe;
        #pragma unroll
        for (int j = 0; j < 4; ++j)
            compose(a[j], b[j], e[j], qa.v[j], qb.v[j], qe.v[j], GLw[j]);
    }
}

// ---- k2c: from group incoming state, rewrite P[c] <- chunk incoming state ----
__global__ __launch_bounds__(256, 2)
void wkv_k2c(float* __restrict__ pa, float* __restrict__ pb,
             float* __restrict__ pe,
             const float* __restrict__ aa, const float* __restrict__ ab,
             const float* __restrict__ ae,
             const float* __restrict__ td, int L)
{
    const uint32_t id  = blockIdx.x * 256u + threadIdx.x;
    const uint32_t ch4 = id & (CH4 - 1);
    const uint32_t g   = id >> 12;
    const uint32_t h0  = (ch4 * 4u) & (HH - 1);

    const f4 wr = *(const f4*)(td + h0);
    const uint32_t gi = g * CH4 + ch4;
    f4 ra = ((const f4*)aa)[gi], rb = ((const f4*)ab)[gi], re = ((const f4*)ae)[gi];
    float Lw[4], a[4], b[4], e[4];
    #pragma unroll
    for (int j = 0; j < 4; ++j) {
        Lw[j] = -__expf(wr.v[j]) * (float)L;
        a[j] = ra.v[j]; b[j] = rb.v[j]; e[j] = re.v[j];
    }

    for (int c = (int)g * CPG; c < (int)(g + 1) * CPG; ++c) {
        const uint32_t i4 = (uint32_t)c * CH4 + ch4;
        const f4 qa = ((const f4*)pa)[i4];
        const f4 qb = ((const f4*)pb)[i4];
        const f4 qe = ((const f4*)pe)[i4];
        f4 oa, ob, oe;
        #pragma unroll
        for (int j = 0; j < 4; ++j) { oa.v[j] = a[j]; ob.v[j] = b[j]; oe.v[j] = e[j]; }
        ((f4*)pa)[i4] = oa; ((f4*)pb)[i4] = ob; ((f4*)pe)[i4] = oe;
        #pragma unroll
        for (int j = 0; j < 4; ++j)
            compose(a[j], b[j], e[j], qa.v[j], qb.v[j], qe.v[j], Lw[j]);
    }
}

// ---- pass3: outputs from incoming state ----
template<int L>
__global__ __launch_bounds__(512, 4)
void wkv_pass3(const float* __restrict__ k_, const float* __restrict__ v_,
               const float* __restrict__ td, const float* __restrict__ tf,
               const float* __restrict__ pa, const float* __restrict__ pb,
               const float* __restrict__ pe,
               float* __restrict__ out)
{
    constexpr uint32_t NCk = TT / L;
    const uint32_t tid = threadIdx.x;
    const uint32_t b   = blockIdx.x / NCk;
    const uint32_t c   = blockIdx.x % NCk;
    const uint32_t h0  = tid * 4u;

    const f4 wr = *(const f4*)(td + h0);
    const f4 ur = *(const f4*)(tf + h0);
    const uint32_t p4 = (c * (uint32_t)BHc + b * (uint32_t)HH) / 4u + tid;
    const f4 ra = ((const f4*)pa)[p4];
    const f4 rb = ((const f4*)pb)[p4];
    const f4 re = ((const f4*)pe)[p4];

    float w[4], u[4], a[4], bs[4], e[4];
    #pragma unroll
    for (int j = 0; j < 4; ++j) {
        w[j] = -__expf(wr.v[j]); u[j] = ur.v[j];
        a[j] = ra.v[j]; bs[j] = rb.v[j]; e[j] = re.v[j];
    }

    const uint32_t off4 = (b * (uint32_t)(TT * HH) + c * (uint32_t)(L * HH)) / 4u + tid;
    const f4* K4 = (const f4*)k_;
    const f4* V4 = (const f4*)v_;
    f4*       O4 = (f4*)out;

    f4 k0 = K4[off4],      v0 = V4[off4];
    f4 k1 = K4[off4 + H4], v1 = V4[off4 + H4];
    #pragma unroll
    for (int t = 0; t < L; ++t) {
        f4 k2, v2;
        if (t + 2 < L) {
            k2 = K4[off4 + (uint32_t)(t + 2) * H4];
            v2 = V4[off4 + (uint32_t)(t + 2) * H4];
        }
        __builtin_amdgcn_sched_barrier(0);
        f4 o;
        #pragma unroll
        for (int j = 0; j < 4; ++j) {
            float kt = k0.v[j], vt = v0.v[j];
            float uk  = u[j] + kt;
            float m   = fmaxf(e[j], uk);
            float wt  = __expf(uk - m);
            float sc  = __expf(e[j] - m);
            float num = fmaf(wt, vt, a[j] * sc);
            float den = fmaf(bs[j], sc, wt);
            o.v[j] = num * __builtin_amdgcn_rcpf(den);
            upd1(a[j], bs[j], e[j], w[j], kt, vt);
        }
        O4[off4 + (uint32_t)t * H4] = o;        // fire-and-forget
        k0 = k1; v0 = v1;
        if (t + 2 < L) { k1 = k2; v1 = v2; }
    }
}

extern "C" void kernel_launch(void* const* d_in, const int* in_sizes, int n_in,
                              void* d_out, int out_size, void* d_ws, size_t ws_size,
                              hipStream_t stream) {
    const float* key   = (const float*)d_in[0];
    const float* value = (const float*)d_in[1];
    const float* td    = (const float*)d_in[2];
    const float* tf    = (const float*)d_in[3];
    float* out = (float*)d_out;

    // workspace: P (3*BH*NC) + A (3*BH*NGRP) floats; NGRP = NC/8
    int NC = 128;
    while (NC > 8 &&
           (size_t)3 * sizeof(float) * BHc * (NC + NC / CPG) > ws_size) NC >>= 1;
    const int L    = TT / NC;
    const int NGRP = NC / CPG;

    float* pa = (float*)d_ws;
    float* pb = pa + (size_t)BHc * NC;
    float* pe = pb + (size_t)BHc * NC;
    float* aa = pe + (size_t)BHc * NC;
    float* ab = aa + (size_t)BHc * NGRP;
    float* ae = ab + (size_t)BHc * NGRP;

    const int gpass = 8 * NC;                    // (b,c) blocks, 512 thr
    const int g2    = CH4 * NGRP / 256;
    const int g2b   = CH4 / 256;

    switch (L) {
    case 16:
        wkv_pass1<16><<<gpass, 512, 0, stream>>>(key, value, td, pa, pb, pe);
        break;
    case 32:
        wkv_pass1<32><<<gpass, 512, 0, stream>>>(key, value, td, pa, pb, pe);
        break;
    default:
        wkv_pass1<64><<<gpass, 512, 0, stream>>>(key, value, td, pa, pb, pe);
        break;
    }
    wkv_k2a<<<g2, 256, 0, stream>>>(pa, pb, pe, aa, ab, ae, td, L);
    wkv_k2b<<<g2b, 256, 0, stream>>>(aa, ab, ae, td, NGRP, L * CPG);
    wkv_k2c<<<g2, 256, 0, stream>>>(pa, pb, pe, aa, ab, ae, td, L);
    switch (L) {
    case 16:
        wkv_pass3<16><<<gpass, 512, 0, stream>>>(key, value, td, tf, pa, pb, pe, out);
        break;
    case 32:
        wkv_pass3<32><<<gpass, 512, 0, stream>>>(key, value, td, tf, pa, pb, pe, out);
        break;
    default:
        wkv_pass3<64><<<gpass, 512, 0, stream>>>(key, value, td, tf, pa, pb, pe, out);
        break;
    }
}